// Round 1
// baseline (477.597 us; speedup 1.0000x reference)
//
#include <hip/hip_runtime.h>
#include <hip/hip_bf16.h>
#include <stdint.h>

#define L_ 2
#define N_ 100000
#define D_ 512
#define B_ 256
#define C_ 10
#define K_ 75
#define NCALI_ 750

typedef unsigned short u16;
typedef __attribute__((ext_vector_type(8))) short short8;
typedef __attribute__((ext_vector_type(4))) float f32x4;

// pack two floats into two rounded bf16s (lo in low 16 bits)
__device__ __forceinline__ unsigned pk_bf16(float lo, float hi) {
  unsigned a = __float_as_uint(lo) + 0x8000u;
  unsigned b = __float_as_uint(hi) + 0x8000u;
  return (a >> 16) | (b & 0xffff0000u);
}

// ---------------- train row 1/norm ----------------
__global__ __launch_bounds__(256) void k_rnorm(const float* __restrict__ tf,
                                               float* __restrict__ rnorm) {
  const int lane = threadIdx.x & 63;
  const long row = (long)blockIdx.x * 4 + (threadIdx.x >> 6);
  const float* p = tf + row * D_;
  float4 a = *(const float4*)(p + lane * 4);
  float4 c = *(const float4*)(p + 256 + lane * 4);
  float ss = a.x*a.x + a.y*a.y + a.z*a.z + a.w*a.w
           + c.x*c.x + c.y*c.y + c.z*c.z + c.w*c.w;
#pragma unroll
  for (int off = 32; off; off >>= 1) ss += __shfl_xor(ss, off);
  if (lane == 0) rnorm[row] = 1.0f / sqrtf(ss);
}

// ---------------- query -> bf16 (raw, no normalization needed) + zero counts ----------------
__global__ __launch_bounds__(256) void k_qprep(const float* __restrict__ qf,
                                               u16* __restrict__ qb,
                                               int* __restrict__ counts) {
  const long i = ((long)blockIdx.x * 256 + threadIdx.x) * 8;
  float4 a = *(const float4*)(qf + i);
  float4 b = *(const float4*)(qf + i + 4);
  uint4 o;
  o.x = pk_bf16(a.x, a.y);
  o.y = pk_bf16(a.z, a.w);
  o.z = pk_bf16(b.x, b.y);
  o.w = pk_bf16(b.z, b.w);
  *(uint4*)(qb + i) = o;
  if (blockIdx.x == 0)
    for (int t = threadIdx.x; t < B_ * C_; t += 256) counts[t] = 0;
}

// ---------------- approx GEMM: scores[b][n] = bf16( q_b . t_hat_n ) ----------------
// BM=256 (all queries), BN=64, BK=32; 4 waves (2m x 2n); train read exactly once.
__global__ __launch_bounds__(256) void k_gemm(const float* __restrict__ tf,
                                              const u16* __restrict__ qb,
                                              const float* __restrict__ rnorm,
                                              u16* __restrict__ scores,
                                              int layer) {
  __shared__ __align__(16) u16 As[256 * 32];
  __shared__ __align__(16) u16 Bs[64 * 32];
  const int tid  = threadIdx.x;
  const int n0   = blockIdx.x * 64;
  const int lane = tid & 63;
  const int wave = tid >> 6;
  const int wr   = wave >> 1;   // m half (128 rows)
  const int wc   = wave & 1;    // n half (32 cols)
  const int kg   = lane >> 4;   // k group 0..3 (8 bf16 each)
  const int rl   = lane & 15;

  const u16*   qbase = qb + (size_t)layer * B_ * D_;
  const float* tbase = tf + (size_t)layer * N_ * D_;
  const float* rn    = rnorm + (size_t)layer * N_;

  const int arow = tid >> 2;  // 0..63
  const int aseg = tid & 3;   // 0..3 (8 elems each)
  const int nb   = n0 + arow;
  const int nc   = nb < N_ ? nb : N_ - 1;
  const float* tsrc = tbase + (size_t)nc * D_ + aseg * 8;
  const float  sc   = rn[nc];
  const u16*   qsrc = qbase + (size_t)arow * D_ + aseg * 8;

  u16* adst = &As[arow * 32 + aseg * 8];
  u16* bdst = &Bs[arow * 32 + aseg * 8];

  const f32x4 vzero = {0.f, 0.f, 0.f, 0.f};
  f32x4 acc[8][2];
#pragma unroll
  for (int i = 0; i < 8; ++i)
#pragma unroll
    for (int j = 0; j < 2; ++j) acc[i][j] = vzero;

  for (int kt = 0; kt < 16; ++kt) {
    const int k0 = kt * 32;
    __syncthreads();
    // stage A (query bf16, 256x32) : 4 chunks of 64 rows
#pragma unroll
    for (int h = 0; h < 4; ++h)
      *(uint4*)(adst + h * 64 * 32) = *(const uint4*)(qsrc + (size_t)h * 64 * D_ + k0);
    // stage B (train fp32 -> scaled bf16, 64x32)
    {
      float4 f0 = *(const float4*)(tsrc + k0);
      float4 f1 = *(const float4*)(tsrc + k0 + 4);
      uint4 o;
      o.x = pk_bf16(f0.x * sc, f0.y * sc);
      o.y = pk_bf16(f0.z * sc, f0.w * sc);
      o.z = pk_bf16(f1.x * sc, f1.y * sc);
      o.w = pk_bf16(f1.z * sc, f1.w * sc);
      *(uint4*)bdst = o;
    }
    __syncthreads();
    short8 af[8], bfr[2];
#pragma unroll
    for (int mf = 0; mf < 8; ++mf)
      af[mf] = *(const short8*)&As[(wr * 128 + mf * 16 + rl) * 32 + kg * 8];
#pragma unroll
    for (int nf = 0; nf < 2; ++nf)
      bfr[nf] = *(const short8*)&Bs[(wc * 32 + nf * 16 + rl) * 32 + kg * 8];
#pragma unroll
    for (int mf = 0; mf < 8; ++mf)
#pragma unroll
      for (int nf = 0; nf < 2; ++nf)
        acc[mf][nf] = __builtin_amdgcn_mfma_f32_16x16x32_bf16(af[mf], bfr[nf], acc[mf][nf], 0, 0, 0);
  }

  const int crow = (lane >> 4) * 4;
#pragma unroll
  for (int mf = 0; mf < 8; ++mf)
#pragma unroll
    for (int nf = 0; nf < 2; ++nf) {
      const int n = n0 + wc * 32 + nf * 16 + rl;
      if (n < N_) {
        const int mb = wr * 128 + mf * 16 + crow;
#pragma unroll
        for (int j = 0; j < 4; ++j) {
          unsigned bits = __float_as_uint(acc[mf][nf][j]) + 0x8000u;
          scores[(size_t)(mb + j) * N_ + n] = (u16)(bits >> 16);
        }
      }
    }
}

// ---------------- per-row selection: histogram -> candidates -> exact fp64 rescore -> rank<75 ----------------
__global__ __launch_bounds__(256) void k_select(const u16* __restrict__ scores,
                                                const float* __restrict__ tf,
                                                const float* __restrict__ qf,
                                                const float* __restrict__ rnorm,
                                                const int* __restrict__ labels,
                                                int* __restrict__ counts,
                                                int layer) {
  __shared__ int    hist[1024];
  __shared__ int    candIdx[2048];
  __shared__ double candVal[2048];
  __shared__ int ncand_s, bin_s;
  const int tid = threadIdx.x;
  const int b   = blockIdx.x;
  const u16*   srow  = scores + (size_t)b * N_;
  const float* tbase = tf + (size_t)layer * N_ * D_;
  const float* q     = qf + (size_t)(layer * B_ + b) * D_;
  const float* rn    = rnorm + (size_t)layer * N_;

  for (int i = tid; i < 1024; i += 256) hist[i] = 0;
  if (tid == 0) ncand_s = 0;
  __syncthreads();

  // pass 1: histogram of bf16 scores (u ~ N(0,1) per row; bins over [-8,8])
  for (int v = tid; v < N_ / 8; v += 256) {
    uint4 p = *(const uint4*)(srow + (size_t)v * 8);
    unsigned w[4] = {p.x, p.y, p.z, p.w};
#pragma unroll
    for (int j = 0; j < 4; ++j) {
      float f0 = __uint_as_float(w[j] << 16);
      float f1 = __uint_as_float(w[j] & 0xffff0000u);
      int b0 = (int)floorf((f0 + 8.f) * 64.f);
      int b1 = (int)floorf((f1 + 8.f) * 64.f);
      b0 = min(max(b0, 0), 1023);
      b1 = min(max(b1, 0), 1023);
      atomicAdd(&hist[b0], 1);
      atomicAdd(&hist[b1], 1);
    }
  }
  __syncthreads();
  if (tid == 0) {
    int cum = 0, bi = 0;
    for (int i = 1023; i >= 0; --i) { cum += hist[i]; if (cum >= K_) { bi = i; break; } }
    bin_s = bi;
  }
  __syncthreads();
  // bin_lo <= 75th-largest approx score; margin 0.06 >> 2*eps(~0.014)
  const float tau = (float)bin_s * (1.f / 64.f) - 8.f - 0.06f;

  // pass 2: collect candidate indices
  for (int v = tid; v < N_ / 8; v += 256) {
    uint4 p = *(const uint4*)(srow + (size_t)v * 8);
    unsigned w[4] = {p.x, p.y, p.z, p.w};
#pragma unroll
    for (int j = 0; j < 4; ++j) {
      float f0 = __uint_as_float(w[j] << 16);
      float f1 = __uint_as_float(w[j] & 0xffff0000u);
      if (f0 >= tau) { int pI = atomicAdd(&ncand_s, 1); if (pI < 2048) candIdx[pI] = v * 8 + j * 2; }
      if (f1 >= tau) { int pI = atomicAdd(&ncand_s, 1); if (pI < 2048) candIdx[pI] = v * 8 + j * 2 + 1; }
    }
  }
  __syncthreads();
  const int m = min(ncand_s, 2048);

  // exact rescore in fp64: one wave per candidate
  const int lane = tid & 63, wave = tid >> 6;
  for (int c = wave; c < m; c += 4) {
    const int n = candIdx[c];
    const float* t = tbase + (size_t)n * D_;
    double s = 0.0;
#pragma unroll
    for (int j = 0; j < 8; ++j) {
      const int d = j * 64 + lane;
      s += (double)q[d] * (double)t[d];
    }
#pragma unroll
    for (int off = 32; off; off >>= 1) s += __shfl_xor(s, off);
    if (lane == 0) candVal[c] = s * (double)rn[n];
  }
  __syncthreads();

  // exact rank (desc score, ties -> lower index first, matching top_k)
  for (int c = tid; c < m; c += 256) {
    const double vc = candVal[c];
    const int ic = candIdx[c];
    int r = 0;
    for (int j = 0; j < m; ++j) {
      const double vj = candVal[j];
      if (vj > vc || (vj == vc && candIdx[j] < ic)) ++r;
    }
    if (r < K_) atomicAdd(&counts[b * C_ + labels[ic]], 1);
  }
}

// ---------------- conformal p-values + credibility ----------------
__global__ __launch_bounds__(1024) void k_final(const int* __restrict__ counts,
                                                const int* __restrict__ cali,
                                                float* __restrict__ out) {
  __shared__ int   cal[NCALI_];
  __shared__ float pv[B_ * C_];
  const int tid = threadIdx.x;
  for (int i = tid; i < NCALI_; i += 1024) cal[i] = cali[i];
  __syncthreads();
  for (int t = tid; t < B_ * C_; t += 1024) {
    const int val = L_ * K_ - counts[t];
    int cnt = 0;
    for (int i = 0; i < NCALI_; ++i) cnt += (cal[i] >= val) ? 1 : 0;
    pv[t] = (float)cnt / (float)NCALI_;
  }
  __syncthreads();
  for (int b = tid; b < B_; b += 1024) {
    float best = pv[b * C_];
    int bc = 0;
#pragma unroll
    for (int c = 1; c < C_; ++c) {
      const float p = pv[b * C_ + c];
      if (p > best) { best = p; bc = c; }
    }
#pragma unroll
    for (int c = 0; c < C_; ++c) out[b * C_ + c] = (c == bc) ? best : 0.f;
  }
}

extern "C" void kernel_launch(void* const* d_in, const int* in_sizes, int n_in,
                              void* d_out, int out_size, void* d_ws, size_t ws_size,
                              hipStream_t stream) {
  (void)in_sizes; (void)n_in; (void)out_size;
  const float* train  = (const float*)d_in[0];
  const float* query  = (const float*)d_in[1];
  const int*   labels = (const int*)d_in[2];
  const int*   cali   = (const int*)d_in[3];
  float* out = (float*)d_out;

  // ws layout (all 256B-aligned offsets)
  char* ws = (char*)d_ws;
  float* rnorm  = (float*)(ws);              //   800,000 B  [L*N]
  u16*   qbf    = (u16*)  (ws + 800000);     //   524,288 B  [L*B*D]
  int*   counts = (int*)  (ws + 1324288);    //    10,240 B  [B*C]
  u16*   scores = (u16*)  (ws + 1334528);    // 51,200,000 B [B*N] (per layer, reused)
  if (ws_size < 52534528u) return;  // insufficient scratch -> fail visibly

  k_rnorm<<<dim3(L_ * N_ / 4), dim3(256), 0, stream>>>(train, rnorm);
  k_qprep<<<dim3(L_ * B_ * D_ / 2048), dim3(256), 0, stream>>>(query, qbf, counts);
  for (int l = 0; l < L_; ++l) {
    k_gemm<<<dim3((N_ + 63) / 64, 1), dim3(256), 0, stream>>>(train, qbf, rnorm, scores, l);
    k_select<<<dim3(B_), dim3(256), 0, stream>>>(scores, train, query, rnorm, labels, counts, l);
  }
  k_final<<<dim3(1), dim3(1024), 0, stream>>>(counts, cali, out);
}